// Round 4
// baseline (1363.512 us; speedup 1.0000x reference)
//
#include <hip/hip_runtime.h>

#define NATOM 128
#define NB    127
#define D0    25
#define D1    50
#define D2    100

// tanh(x) = 1 - 2/(exp(2x)+1); exact at +-inf, ~1e-6 rel err.
__device__ __forceinline__ float fast_tanh(float x) {
    float e = __expf(2.0f * x);
    return 1.0f - 2.0f * __builtin_amdgcn_rcpf(e + 1.0f);
}

__global__ __launch_bounds__(128, 3) void feat_kernel(
    const float* __restrict__ coords,
    const int*   __restrict__ types,
    const float* __restrict__ W0, const float* __restrict__ B0,
    const float* __restrict__ W1, const float* __restrict__ B1,
    const float* __restrict__ W2, const float* __restrict__ B2,
    float* __restrict__ out)
{
    // Total LDS ~3.5 KB -> occupancy is VGPR-limited, not LDS-limited.
    __shared__ int   St[NB];
    __shared__ int   Sj[128];
    __shared__ float Mp[2][3][D2];   // per-wave partial M; every entry written once

    const int bn = blockIdx.x;       // b*128 + n
    const int b  = bn >> 7;
    const int n  = bn & 127;
    const int k  = threadIdx.x;
    const int wv = k >> 6;

    // ---- stable sort of neighbors by type: wave-coherent weight loads.
    //      k-contractions are permutation-invariant -> result identical.
    if (k < NB) {
        const int j0 = k + (k >= n ? 1 : 0);    // skip self
        St[k] = types[j0];
    } else {
        // fake slot 127: valid geometry (no NaN), flagged not-real -> E = 0
        Sj[127] = (((n + 1) & 127) << 3);       // real bit (bit2) = 0, type 0
    }
    __syncthreads();
    if (k < NB) {
        const int j0 = k + (k >= n ? 1 : 0);
        const int tj = St[k];
        int rank = 0;
        #pragma unroll 4
        for (int kk = 0; kk < NB; ++kk) {
            const int t2 = St[kk];              // broadcast read
            rank += ((t2 < tj) || (t2 == tj && kk < k)) ? 1 : 0;
        }
        Sj[rank] = (j0 << 3) | 4 | tj;          // bit2 = real
    }
    __syncthreads();

    const int pj  = Sj[k];
    const int jj  = pj >> 3;
    const int idx = (types[n] << 2) | (pj & 3);
    const float rmask = (pj & 4) ? 1.0f : 0.0f;

    const float cx = coords[(b * NATOM + n) * 3 + 0];
    const float cy = coords[(b * NATOM + n) * 3 + 1];
    const float cz = coords[(b * NATOM + n) * 3 + 2];
    const float dx = cx - coords[(b * NATOM + jj) * 3 + 0];
    const float dy = cy - coords[(b * NATOM + jj) * 3 + 1];
    const float dz = cz - coords[(b * NATOM + jj) * 3 + 2];
    const float d2   = dx * dx + dy * dy + dz * dz;
    const float inv  = rsqrtf(d2);              // 1/d (= env_r)
    const float inv2 = inv * inv;
    const float Ex = dx * inv2 * rmask;         // env_a, zeroed on fake lane
    const float Ey = dy * inv2 * rmask;
    const float Ez = dz * inv2 * rmask;

    float h1[D1];   // compile-time-indexed only -> stays in VGPRs

    // ---- layer 0: 1 -> 25
    float h0[D0];
    {
        const float* w  = W0 + idx * D0;
        const float* bb = B0 + idx * D0;
        #pragma unroll
        for (int o = 0; o < D0; ++o)
            h0[o] = fast_tanh(w[o] * inv + bb[o]);
    }

    // ---- layer 1: 25 -> 50 in 5 chunks of 10
    {
        const float* w  = W1 + idx * D1 * D0;
        const float* bb = B1 + idx * D1;
        #pragma unroll
        for (int oc = 0; oc < D1; oc += 10) {
            float acc[10];
            #pragma unroll
            for (int uu = 0; uu < 10; ++uu) acc[uu] = bb[oc + uu];
            #pragma unroll
            for (int i = 0; i < D0; ++i) {
                const float hv = h0[i];
                #pragma unroll
                for (int uu = 0; uu < 10; ++uu)
                    acc[uu] += w[(oc + uu) * D0 + i] * hv;
            }
            #pragma unroll
            for (int uu = 0; uu < 10; ++uu)
                h1[oc + uu] = fast_tanh(acc[uu]) + h0[(oc + uu) % D0];
        }
    }

    // ---- layer 2 fused with the M-reduction (no G materialization).
    //      M[c][o] = sum_k E_c[k] * G[k][o]; per 5-output chunk each wave
    //      butterfly-reduces 15 partials, lane 0 writes Mp[wv].
    //      Outer half-loop h in {0,1}: (h*50+base+u) % 50 == base+u, so all
    //      h1[] reads keep compile-time indices with a rolled outer loop.
    {
        const float* w  = W2 + idx * (D2 * D1);
        const float* bb = B2 + idx * D2;
        #pragma unroll 1
        for (int h = 0; h < 2; ++h) {
            const float* wh = w  + h * (50 * D1);
            const float* bh = bb + h * 50;
            float* mp0 = &Mp[wv][0][h * 50];
            float* mp1 = &Mp[wv][1][h * 50];
            float* mp2 = &Mp[wv][2][h * 50];
            #pragma unroll
            for (int base = 0; base < 50; base += 5) {
                float acc[5];
                #pragma unroll
                for (int u = 0; u < 5; ++u) acc[u] = bh[base + u];
                #pragma unroll
                for (int i = 0; i < D1 / 2; ++i) {
                    const float e0 = h1[2 * i], e1 = h1[2 * i + 1]; // const idx
                    #pragma unroll
                    for (int u = 0; u < 5; ++u) {
                        // rows are 200 B apart -> float2 stays 8B-aligned
                        const float2 ww =
                            *(const float2*)(wh + (base + u) * D1 + 2 * i);
                        acc[u] += ww.x * e0 + ww.y * e1;
                    }
                }
                float p[15];
                #pragma unroll
                for (int u = 0; u < 5; ++u) {
                    const float g = fast_tanh(acc[u]) + h1[base + u]; // residual
                    p[u]      = Ex * g;
                    p[u + 5]  = Ey * g;
                    p[u + 10] = Ez * g;
                }
                #pragma unroll
                for (int s = 1; s < 64; s <<= 1) {
                    #pragma unroll
                    for (int v = 0; v < 15; ++v)
                        p[v] += __shfl_xor(p[v], s, 64);
                }
                if ((k & 63) == 0) {
                    #pragma unroll
                    for (int u = 0; u < 5; ++u) {
                        mp0[base + u] = p[u];
                        mp1[base + u] = p[u + 5];
                        mp2[base + u] = p[u + 10];
                    }
                }
            }
        }
    }
    __syncthreads();

    // ---- final quadratic: out[m][a] = sum_c M[c][m] * M[c][a], a < 4
    if (k < D2) {
        const float m0 = Mp[0][0][k] + Mp[1][0][k];
        const float m1 = Mp[0][1][k] + Mp[1][1][k];
        const float m2 = Mp[0][2][k] + Mp[1][2][k];
        float4 o4;
        o4.x = m0 * (Mp[0][0][0] + Mp[1][0][0]) + m1 * (Mp[0][1][0] + Mp[1][1][0])
             + m2 * (Mp[0][2][0] + Mp[1][2][0]);
        o4.y = m0 * (Mp[0][0][1] + Mp[1][0][1]) + m1 * (Mp[0][1][1] + Mp[1][1][1])
             + m2 * (Mp[0][2][1] + Mp[1][2][1]);
        o4.z = m0 * (Mp[0][0][2] + Mp[1][0][2]) + m1 * (Mp[0][1][2] + Mp[1][1][2])
             + m2 * (Mp[0][2][2] + Mp[1][2][2]);
        o4.w = m0 * (Mp[0][0][3] + Mp[1][0][3]) + m1 * (Mp[0][1][3] + Mp[1][1][3])
             + m2 * (Mp[0][2][3] + Mp[1][2][3]);
        reinterpret_cast<float4*>(out)[bn * D2 + k] = o4;   // 16B-aligned
    }
}

extern "C" void kernel_launch(void* const* d_in, const int* in_sizes, int n_in,
                              void* d_out, int out_size, void* d_ws, size_t ws_size,
                              hipStream_t stream) {
    (void)in_sizes; (void)n_in; (void)out_size; (void)d_ws; (void)ws_size;
    const float* coords = (const float*)d_in[0];
    const int*   types  = (const int*)  d_in[1];
    const float* W0 = (const float*)d_in[2];
    const float* B0 = (const float*)d_in[3];
    const float* W1 = (const float*)d_in[4];
    const float* B1 = (const float*)d_in[5];
    const float* W2 = (const float*)d_in[6];
    const float* B2 = (const float*)d_in[7];
    float* out = (float*)d_out;

    feat_kernel<<<64 * NATOM, 128, 0, stream>>>(
        coords, types, W0, B0, W1, B1, W2, B2, out);
}

// Round 6
// 668.235 us; speedup vs baseline: 2.0405x; 2.0405x over previous
//
#include <hip/hip_runtime.h>
#include <hip/hip_bf16.h>

#define NATOM 128
#define NB    127
#define D0    25
#define D1    50
#define D2    100
#define HSTR  72     // H1b row stride in bf16 units (144 B = 9*16: rows 16B-aligned)
#define MROWS 192    // max padded rows = 127 + 4*15 = 187

typedef __attribute__((ext_vector_type(8))) short  short8;   // 8 bf16 = 4 VGPRs
typedef __attribute__((ext_vector_type(4))) float  f32x4;

// tanh(x) = 1 - 2/(exp(2x)+1); exact at +-inf, ~1e-6 rel err.
__device__ __forceinline__ float fast_tanh(float x) {
    float e = __expf(2.0f * x);
    return 1.0f - 2.0f * __builtin_amdgcn_rcpf(e + 1.0f);
}
__device__ __forceinline__ short f2bf(float f) {
    __hip_bfloat16 h = __float2bfloat16(f);      // RNE
    return *reinterpret_cast<short*>(&h);
}
__device__ __forceinline__ float bf2f(short s) {
    return __uint_as_float(((unsigned int)(unsigned short)s) << 16);
}

__global__ __launch_bounds__(128, 1) void feat_kernel(
    const float* __restrict__ coords,
    const int*   __restrict__ types,
    const float* __restrict__ W0, const float* __restrict__ B0,
    const float* __restrict__ W1, const float* __restrict__ B1,
    const float* __restrict__ W2, const float* __restrict__ B2,
    float* __restrict__ out)
{
    // 27648 + 3072 + 1344 = 32064 B -> 5 blocks/CU
    __shared__ __attribute__((aligned(16))) short H1b[MROWS][HSTR];
    __shared__ float4 E4[MROWS];          // env_a (w=0); zero on pad rows
    __shared__ union {
        struct { int St[NB]; int Sj[NB]; } s;   // sort scratch (early only)
        float Ms[3][112];                       // M result (late only)
    } u;

    const int bn = blockIdx.x;    // b*128 + n
    const int b  = bn >> 7;
    const int n  = bn & 127;
    const int k  = threadIdx.x;
    const int wv = k >> 6;
    const int lq = (k >> 4) & 3;  // quad within wave
    const int ln = k & 15;

    // ---- zero H1b (pad rows AND cols 50..71 must be 0) and E4
    {
        uint2* p = (uint2*)&H1b[0][0];
        const uint2 z2 = {0u, 0u};
        for (int i = k; i < (MROWS * HSTR * 2) / 8; i += 128) p[i] = z2;
        const float4 z4 = make_float4(0.f, 0.f, 0.f, 0.f);
        for (int i = k; i < MROWS; i += 128) E4[i] = z4;
    }
    if (k < NB) {
        const int j0 = k + (k >= n ? 1 : 0);   // skip self
        u.s.St[k] = types[j0];
    }
    __syncthreads();

    // ---- type counts (all threads) + stable rank sort (k < NB)
    int c0 = 0, c1 = 0, c2 = 0, c3 = 0;
    {
        const int tj = (k < NB) ? u.s.St[k] : -1;
        int rank = 0;
        #pragma unroll 4
        for (int kk = 0; kk < NB; ++kk) {
            const int t2 = u.s.St[kk];         // broadcast read
            c0 += (t2 == 0); c1 += (t2 == 1); c2 += (t2 == 2); c3 += (t2 == 3);
            rank += ((t2 < tj) || (t2 == tj && kk < k)) ? 1 : 0;
        }
        if (k < NB) {
            const int j0 = k + (k >= n ? 1 : 0);
            u.s.Sj[rank] = (j0 << 2) | tj;
        }
    }
    __syncthreads();

    // padded segment starts (every thread has counts in registers)
    const int cum1 = c0, cum2 = c0 + c1, cum3 = c0 + c1 + c2;
    const int ps1 = (c0 + 15) & ~15;
    const int ps2 = ps1 + ((c1 + 15) & ~15);
    const int ps3 = ps2 + ((c2 + 15) & ~15);
    const int tn  = types[n];

    float h1[D1];   // compile-time-indexed only

    // ======== phase 1: per-pair fp32 layers 0/1 (thread = sorted pair) ======
    if (k < NB) {
        const int pj  = u.s.Sj[k];
        const int jj  = pj >> 2;
        const int tj2 = pj & 3;
        const int idx = (tn << 2) | tj2;
        const int cumt = (tj2 == 0) ? 0 : (tj2 == 1) ? cum1 : (tj2 == 2) ? cum2 : cum3;
        const int pst  = (tj2 == 0) ? 0 : (tj2 == 1) ? ps1  : (tj2 == 2) ? ps2  : ps3;
        const int pr   = pst + (k - cumt);     // padded row for this pair

        const float cx = coords[(b * NATOM + n) * 3 + 0];
        const float cy = coords[(b * NATOM + n) * 3 + 1];
        const float cz = coords[(b * NATOM + n) * 3 + 2];
        const float dx = cx - coords[(b * NATOM + jj) * 3 + 0];
        const float dy = cy - coords[(b * NATOM + jj) * 3 + 1];
        const float dz = cz - coords[(b * NATOM + jj) * 3 + 2];
        const float d2   = dx * dx + dy * dy + dz * dz;
        const float inv  = rsqrtf(d2);         // 1/d (= env_r)
        const float inv2 = inv * inv;
        E4[pr] = make_float4(dx * inv2, dy * inv2, dz * inv2, 0.f);

        // layer 0: 1 -> 25 (wave-coherent weight loads after sort)
        float h0[D0];
        {
            const float* w  = W0 + idx * D0;
            const float* bb = B0 + idx * D0;
            #pragma unroll
            for (int o = 0; o < D0; ++o)
                h0[o] = fast_tanh(w[o] * inv + bb[o]);
        }
        // layer 1: 25 -> 50 in 5 chunks of 10
        {
            const float* w  = W1 + idx * D1 * D0;
            const float* bb = B1 + idx * D1;
            #pragma unroll
            for (int oc = 0; oc < D1; oc += 10) {
                float acc[10];
                #pragma unroll
                for (int uu = 0; uu < 10; ++uu) acc[uu] = bb[oc + uu];
                #pragma unroll
                for (int i = 0; i < D0; ++i) {
                    const float hv = h0[i];
                    #pragma unroll
                    for (int uu = 0; uu < 10; ++uu)
                        acc[uu] += w[(oc + uu) * D0 + i] * hv;
                }
                #pragma unroll
                for (int uu = 0; uu < 10; ++uu)
                    h1[oc + uu] = fast_tanh(acc[uu]) + h0[(oc + uu) % D0];
            }
        }
        // store h1 row as packed bf16 pairs (cols 50..71 stay 0)
        unsigned int* dst = (unsigned int*)&H1b[pr][0];
        #pragma unroll
        for (int o = 0; o < D1; o += 2) {
            const unsigned int lo = (unsigned short)f2bf(h1[o]);
            const unsigned int hi = (unsigned short)f2bf(h1[o + 1]);
            dst[o >> 1] = lo | (hi << 16);
        }
    }
    __syncthreads();

    // ======== phase 2: layer 2 via MFMA, fused with M-reduction ============
    // D[m][o] = sum_k H1b[m][k] * W2[idx][o][k].
    // A-frag (verified m120 layout): lane holds A[m=lane&15][k=quad*8+j]
    //   -> ds_read_b128 at &H1b[mb+ln][lq*8] (+32 for the second MFMA).
    // B-frag: B[k=quad*8+j][n=lane&15], n = o -> W2 row o, cols lq*8+j.
    // C/D (verified m89/m91): col=lane&15 (=o), row=quad*4+reg (=m).
    // G = tanh(D + b2) + h1[o%50]; Mc[c] += E[c][m]*G; pad rows have E=0.
    for (int nt = wv; nt < 7; nt += 2) {       // N-tiles split across 2 waves
        const int o  = nt * 16 + ln;           // this lane's output neuron
        const bool ov = (o < D2);
        const int rres = o % D1;               // residual column
        float Mc0 = 0.f, Mc1 = 0.f, Mc2 = 0.f;
        #pragma unroll
        for (int t = 0; t < 4; ++t) {
            const int cnt = (t == 0) ? c0 : (t == 1) ? c1 : (t == 2) ? c2 : c3;
            if (cnt == 0) continue;
            const int ps  = (t == 0) ? 0 : (t == 1) ? ps1 : (t == 2) ? ps2 : ps3;
            const int idx = (tn << 2) | t;
            const float* wr = W2 + idx * (D2 * D1) + o * D1;
            short8 bf0, bf1;
            #pragma unroll
            for (int j = 0; j < 8; ++j) {
                const int i0 = lq * 8 + j;             // < 32 < 50: always valid
                const int i1 = 32 + lq * 8 + j;        // may exceed 49
                bf0[j] = ov ? f2bf(wr[i0]) : (short)0;
                bf1[j] = (ov && i1 < D1) ? f2bf(wr[i1]) : (short)0;
            }
            const float b2n = ov ? B2[idx * D2 + o] : 0.f;
            const int mtiles = (cnt + 15) >> 4;
            for (int mt = 0; mt < mtiles; ++mt) {
                const int mb = ps + mt * 16;
                const short* arow = &H1b[mb + ln][0];
                // FIX (round 5 bug): A-frag needs the per-quad K-slice offset.
                const short8 af0 = *(const short8*)(arow + lq * 8);      // k=lq*8+j
                const short8 af1 = *(const short8*)(arow + 32 + lq * 8); // +32
                f32x4 d = {0.f, 0.f, 0.f, 0.f};
                d = __builtin_amdgcn_mfma_f32_16x16x32_bf16(af0, bf0, d, 0, 0, 0);
                d = __builtin_amdgcn_mfma_f32_16x16x32_bf16(af1, bf1, d, 0, 0, 0);
                #pragma unroll
                for (int r = 0; r < 4; ++r) {          // C/D: row = quad*4+r
                    const int m = mb + lq * 4 + r;
                    const float4 e = E4[m];
                    const float g = fast_tanh(d[r] + b2n) + bf2f(H1b[m][rres]);
                    Mc0 += e.x * g; Mc1 += e.y * g; Mc2 += e.z * g;
                }
            }
        }
        // reduce across the 4 quads (rows); lanes differ only in lq
        Mc0 += __shfl_xor(Mc0, 16, 64); Mc1 += __shfl_xor(Mc1, 16, 64);
        Mc2 += __shfl_xor(Mc2, 16, 64);
        Mc0 += __shfl_xor(Mc0, 32, 64); Mc1 += __shfl_xor(Mc1, 32, 64);
        Mc2 += __shfl_xor(Mc2, 32, 64);
        if (lq == 0) {
            u.Ms[0][o] = Mc0; u.Ms[1][o] = Mc1; u.Ms[2][o] = Mc2;
        }
    }
    __syncthreads();

    // ======== phase 3: out[m][a] = sum_c M[c][m] * M[c][a], a < 4 ==========
    if (k < D2) {
        const float m0 = u.Ms[0][k], m1 = u.Ms[1][k], m2 = u.Ms[2][k];
        float4 o4;
        o4.x = m0 * u.Ms[0][0] + m1 * u.Ms[1][0] + m2 * u.Ms[2][0];
        o4.y = m0 * u.Ms[0][1] + m1 * u.Ms[1][1] + m2 * u.Ms[2][1];
        o4.z = m0 * u.Ms[0][2] + m1 * u.Ms[1][2] + m2 * u.Ms[2][2];
        o4.w = m0 * u.Ms[0][3] + m1 * u.Ms[1][3] + m2 * u.Ms[2][3];
        reinterpret_cast<float4*>(out)[bn * D2 + k] = o4;   // 16B-aligned
    }
}

extern "C" void kernel_launch(void* const* d_in, const int* in_sizes, int n_in,
                              void* d_out, int out_size, void* d_ws, size_t ws_size,
                              hipStream_t stream) {
    (void)in_sizes; (void)n_in; (void)out_size; (void)d_ws; (void)ws_size;
    const float* coords = (const float*)d_in[0];
    const int*   types  = (const int*)  d_in[1];
    const float* W0 = (const float*)d_in[2];
    const float* B0 = (const float*)d_in[3];
    const float* W1 = (const float*)d_in[4];
    const float* B1 = (const float*)d_in[5];
    const float* W2 = (const float*)d_in[6];
    const float* B2 = (const float*)d_in[7];
    float* out = (float*)d_out;

    feat_kernel<<<64 * NATOM, 128, 0, stream>>>(
        coords, types, W0, B0, W1, B1, W2, B2, out);
}

// Round 7
// 471.481 us; speedup vs baseline: 2.8920x; 1.4173x over previous
//
#include <hip/hip_runtime.h>
#include <hip/hip_bf16.h>

#define NATOM 128
#define NB    127
#define D0    25
#define D1    50
#define D2    100
#define H0STR 40     // shorts; 80 B = 5*16 -> rows 16B-aligned; 20 dw mod 32 -> 2-way max
#define H1STR 72     // shorts; 144 B = 9*16 -> 16B-aligned; A-frag pattern conflict-free
#define MROWS 192    // max padded rows = 127 + 4*15 = 187

typedef __attribute__((ext_vector_type(8))) short  short8;   // 8 bf16 = 4 VGPRs
typedef __attribute__((ext_vector_type(4))) float  f32x4;

// tanh(x) = 1 - 2/(exp(2x)+1); exact at +-inf, ~1e-6 rel err.
__device__ __forceinline__ float fast_tanh(float x) {
    float e = __expf(2.0f * x);
    return 1.0f - 2.0f * __builtin_amdgcn_rcpf(e + 1.0f);
}
__device__ __forceinline__ short f2bf(float f) {
    __hip_bfloat16 h = __float2bfloat16(f);      // RNE
    return *reinterpret_cast<short*>(&h);
}
__device__ __forceinline__ float bf2f(short s) {
    return __uint_as_float(((unsigned int)(unsigned short)s) << 16);
}

__global__ __launch_bounds__(256, 1) void feat_kernel(
    const float* __restrict__ coords,
    const int*   __restrict__ types,
    const float* __restrict__ W0, const float* __restrict__ B0,
    const float* __restrict__ W1, const float* __restrict__ B1,
    const float* __restrict__ W2, const float* __restrict__ B2,
    float* __restrict__ out)
{
    // 27648 + 15360 + 3072 + 1344 = 47424 B -> 3 blocks/CU x 4 waves = 12 waves/CU
    __shared__ __attribute__((aligned(16))) short H1b[MROWS][H1STR];
    __shared__ __attribute__((aligned(16))) short H0b[MROWS][H0STR];
    __shared__ float4 E4[MROWS];          // env_a (w=0); zero on pad rows = the mask
    __shared__ union {
        struct { int St[NB]; int Sj[NB]; } s;   // sort scratch (early only)
        float Ms[3][112];                       // M result (late only)
    } u;

    const int bn = blockIdx.x;    // b*128 + n
    const int b  = bn >> 7;
    const int n  = bn & 127;
    const int k  = threadIdx.x;   // 0..255
    const int wv = k >> 6;        // wave 0..3
    const int lq = (k >> 4) & 3;  // quad within wave
    const int ln = k & 15;

    // ---- zero LDS: H0b fully (pad rows/cols feed MFMA -> must be 0, never NaN),
    //      H1b fully (cols 50..63 are K-zeros for layer-2), E4 (pad-row mask).
    {
        const uint2 z2 = {0u, 0u};
        uint2* p1 = (uint2*)&H1b[0][0];
        for (int i = k; i < (MROWS * H1STR) / 4; i += 256) p1[i] = z2;
        uint2* p0 = (uint2*)&H0b[0][0];
        for (int i = k; i < (MROWS * H0STR) / 4; i += 256) p0[i] = z2;
        const float4 z4 = make_float4(0.f, 0.f, 0.f, 0.f);
        for (int i = k; i < MROWS; i += 256) E4[i] = z4;
    }
    if (k < NB) {
        const int j0 = k + (k >= n ? 1 : 0);   // skip self
        u.s.St[k] = types[j0];
    }
    __syncthreads();

    // ---- type counts (all threads) + stable rank sort (k < NB)
    int c0 = 0, c1 = 0, c2 = 0, c3 = 0;
    {
        const int tj = (k < NB) ? u.s.St[k] : -1;
        int rank = 0;
        #pragma unroll 4
        for (int kk = 0; kk < NB; ++kk) {
            const int t2 = u.s.St[kk];         // broadcast read
            c0 += (t2 == 0); c1 += (t2 == 1); c2 += (t2 == 2); c3 += (t2 == 3);
            rank += ((t2 < tj) || (t2 == tj && kk < k)) ? 1 : 0;
        }
        if (k < NB) {
            const int j0 = k + (k >= n ? 1 : 0);
            u.s.Sj[rank] = (j0 << 2) | tj;
        }
    }
    __syncthreads();

    const int cum1 = c0, cum2 = c0 + c1, cum3 = c0 + c1 + c2;
    const int ps1 = (c0 + 15) & ~15;
    const int ps2 = ps1 + ((c1 + 15) & ~15);
    const int ps3 = ps2 + ((c2 + 15) & ~15);
    const int tn  = types[n];

    // ======== phase 1: geometry + layer 0 only (k = sorted pair) ===========
    if (k < NB) {
        const int pj  = u.s.Sj[k];
        const int jj  = pj >> 2;
        const int tj2 = pj & 3;
        const int idx = (tn << 2) | tj2;
        const int cumt = (tj2 == 0) ? 0 : (tj2 == 1) ? cum1 : (tj2 == 2) ? cum2 : cum3;
        const int pst  = (tj2 == 0) ? 0 : (tj2 == 1) ? ps1  : (tj2 == 2) ? ps2  : ps3;
        const int pr   = pst + (k - cumt);     // padded row for this pair

        const float cx = coords[(b * NATOM + n) * 3 + 0];
        const float cy = coords[(b * NATOM + n) * 3 + 1];
        const float cz = coords[(b * NATOM + n) * 3 + 2];
        const float dx = cx - coords[(b * NATOM + jj) * 3 + 0];
        const float dy = cy - coords[(b * NATOM + jj) * 3 + 1];
        const float dz = cz - coords[(b * NATOM + jj) * 3 + 2];
        const float d2   = dx * dx + dy * dy + dz * dz;
        const float inv  = rsqrtf(d2);         // 1/d (= env_r)
        const float inv2 = inv * inv;
        E4[pr] = make_float4(dx * inv2, dy * inv2, dz * inv2, 0.f);

        // layer 0: 1 -> 25 (wave-coherent weight loads after sort)
        const float* w  = W0 + idx * D0;
        const float* bb = B0 + idx * D0;
        float h0[D0];
        #pragma unroll
        for (int o = 0; o < D0; ++o)
            h0[o] = fast_tanh(w[o] * inv + bb[o]);

        // store h0 bf16 (cols 25..31 stay 0 = K-pad for the 16x16x32 MFMA)
        unsigned int* dst = (unsigned int*)&H0b[pr][0];
        #pragma unroll
        for (int o = 0; o < D0 - 1; o += 2) {
            const unsigned int lo = (unsigned short)f2bf(h0[o]);
            const unsigned int hi = (unsigned short)f2bf(h0[o + 1]);
            dst[o >> 1] = lo | (hi << 16);
        }
        dst[12] = (unsigned int)(unsigned short)f2bf(h0[24]);   // hi half = 0
    }
    __syncthreads();

    // ======== phase 2a: layer 1 via MFMA (25 -> 50), K padded to 32 ========
    // Wave wv owns N-tile nt1 = wv (o1 = wv*16+ln), loops all 4 types: the
    // per-wave M-tile total is identical across waves -> balanced.
    // A[m=ln][k=lq*8+j] from H0b (b128); B[k][o1] from W1 global (bf16 cvt).
    // C/D: col=ln (=o1), row=lq*4+r (=m). Pad rows produce finite garbage h1,
    // masked later by E=0 in the M-reduction.
    {
        const int o1   = wv * 16 + ln;         // 0..63
        const bool ov1 = (o1 < D1);
        const int rres1 = (o1 < D0) ? o1 : o1 - D0;   // o1 % 25
        #pragma unroll
        for (int t = 0; t < 4; ++t) {
            const int cnt = (t == 0) ? c0 : (t == 1) ? c1 : (t == 2) ? c2 : c3;
            if (cnt == 0) continue;
            const int ps  = (t == 0) ? 0 : (t == 1) ? ps1 : (t == 2) ? ps2 : ps3;
            const int idx = (tn << 2) | t;
            const float* wr = W1 + idx * (D1 * D0) + o1 * D0;
            short8 bf;
            #pragma unroll
            for (int j = 0; j < 8; ++j) {
                const int i = lq * 8 + j;
                bf[j] = (ov1 && i < D0) ? f2bf(wr[i]) : (short)0;
            }
            const float b1v = ov1 ? B1[idx * D1 + o1] : 0.f;
            const int mtiles = (cnt + 15) >> 4;
            for (int mt = 0; mt < mtiles; ++mt) {
                const int mb = ps + mt * 16;
                const short8 af = *(const short8*)(&H0b[mb + ln][lq * 8]);
                f32x4 d = {0.f, 0.f, 0.f, 0.f};
                d = __builtin_amdgcn_mfma_f32_16x16x32_bf16(af, bf, d, 0, 0, 0);
                if (ov1) {                      // never touch cols >= 50 of H1b
                    #pragma unroll
                    for (int r = 0; r < 4; ++r) {
                        const int m = mb + lq * 4 + r;
                        const float h1v =
                            fast_tanh(d[r] + b1v) + bf2f(H0b[m][rres1]);
                        H1b[m][o1] = f2bf(h1v);
                    }
                }
            }
        }
    }
    __syncthreads();

    // ======== phase 2b: layer 2 via MFMA (50 -> 100) + fused M-reduce ======
    for (int nt = wv; nt < 7; nt += 4) {
        const int o  = nt * 16 + ln;           // output neuron
        const bool ov = (o < D2);
        const int rres = o % D1;               // residual column
        float Mc0 = 0.f, Mc1 = 0.f, Mc2 = 0.f;
        #pragma unroll
        for (int t = 0; t < 4; ++t) {
            const int cnt = (t == 0) ? c0 : (t == 1) ? c1 : (t == 2) ? c2 : c3;
            if (cnt == 0) continue;
            const int ps  = (t == 0) ? 0 : (t == 1) ? ps1 : (t == 2) ? ps2 : ps3;
            const int idx = (tn << 2) | t;
            const float* wr = W2 + idx * (D2 * D1) + o * D1;
            short8 bf0, bf1;
            #pragma unroll
            for (int j = 0; j < 8; ++j) {
                const int i0 = lq * 8 + j;             // < 32 < 50: always valid
                const int i1 = 32 + lq * 8 + j;        // may exceed 49
                bf0[j] = ov ? f2bf(wr[i0]) : (short)0;
                bf1[j] = (ov && i1 < D1) ? f2bf(wr[i1]) : (short)0;
            }
            const float b2n = ov ? B2[idx * D2 + o] : 0.f;
            const int mtiles = (cnt + 15) >> 4;
            for (int mt = 0; mt < mtiles; ++mt) {
                const int mb = ps + mt * 16;
                const short* arow = &H1b[mb + ln][0];
                const short8 af0 = *(const short8*)(arow + lq * 8);      // k=lq*8+j
                const short8 af1 = *(const short8*)(arow + 32 + lq * 8); // +32
                f32x4 d = {0.f, 0.f, 0.f, 0.f};
                d = __builtin_amdgcn_mfma_f32_16x16x32_bf16(af0, bf0, d, 0, 0, 0);
                d = __builtin_amdgcn_mfma_f32_16x16x32_bf16(af1, bf1, d, 0, 0, 0);
                #pragma unroll
                for (int r = 0; r < 4; ++r) {          // C/D: row = quad*4+r
                    const int m = mb + lq * 4 + r;
                    const float4 e = E4[m];            // 0 on pad rows = mask
                    const float g = fast_tanh(d[r] + b2n) + bf2f(H1b[m][rres]);
                    Mc0 += e.x * g; Mc1 += e.y * g; Mc2 += e.z * g;
                }
            }
        }
        // reduce across the 4 quads (rows); lanes differ only in lq
        Mc0 += __shfl_xor(Mc0, 16, 64); Mc1 += __shfl_xor(Mc1, 16, 64);
        Mc2 += __shfl_xor(Mc2, 16, 64);
        Mc0 += __shfl_xor(Mc0, 32, 64); Mc1 += __shfl_xor(Mc1, 32, 64);
        Mc2 += __shfl_xor(Mc2, 32, 64);
        if (lq == 0 && ov) {
            u.Ms[0][o] = Mc0; u.Ms[1][o] = Mc1; u.Ms[2][o] = Mc2;
        }
    }
    __syncthreads();

    // ======== phase 3: out[m][a] = sum_c M[c][m] * M[c][a], a < 4 ==========
    if (k < D2) {
        const float m0 = u.Ms[0][k], m1 = u.Ms[1][k], m2 = u.Ms[2][k];
        float4 o4;
        o4.x = m0 * u.Ms[0][0] + m1 * u.Ms[1][0] + m2 * u.Ms[2][0];
        o4.y = m0 * u.Ms[0][1] + m1 * u.Ms[1][1] + m2 * u.Ms[2][1];
        o4.z = m0 * u.Ms[0][2] + m1 * u.Ms[1][2] + m2 * u.Ms[2][2];
        o4.w = m0 * u.Ms[0][3] + m1 * u.Ms[1][3] + m2 * u.Ms[2][3];
        reinterpret_cast<float4*>(out)[bn * D2 + k] = o4;   // 16B-aligned
    }
}

extern "C" void kernel_launch(void* const* d_in, const int* in_sizes, int n_in,
                              void* d_out, int out_size, void* d_ws, size_t ws_size,
                              hipStream_t stream) {
    (void)in_sizes; (void)n_in; (void)out_size; (void)d_ws; (void)ws_size;
    const float* coords = (const float*)d_in[0];
    const int*   types  = (const int*)  d_in[1];
    const float* W0 = (const float*)d_in[2];
    const float* B0 = (const float*)d_in[3];
    const float* W1 = (const float*)d_in[4];
    const float* B1 = (const float*)d_in[5];
    const float* W2 = (const float*)d_in[6];
    const float* B2 = (const float*)d_in[7];
    float* out = (float*)d_out;

    feat_kernel<<<64 * NATOM, 256, 0, stream>>>(
        coords, types, W0, B0, W1, B1, W2, B2, out);
}

// Round 8
// 215.065 us; speedup vs baseline: 6.3400x; 2.1923x over previous
//
#include <hip/hip_runtime.h>
#include <hip/hip_bf16.h>

#define NATOM 128
#define NB    127
#define D0    25
#define D1    50
#define D2    100
#define H0STR 40     // shorts; 80 B = 5*16 -> rows 16B-aligned
#define H1STR 72     // shorts; 144 B = 9*16 -> 16B-aligned; A-frag conflict-free
#define MROWS 192    // max padded rows = 127 + 4*15 = 187
#define W1B_SHORTS (16 * 50 * 32)     // 25600  (K 25 -> 32, zero-padded)
#define W2B_SHORTS (16 * 100 * 64)    // 102400 (K 50 -> 64, zero-padded)

typedef __attribute__((ext_vector_type(8))) short  short8;   // 8 bf16 = 4 VGPRs
typedef __attribute__((ext_vector_type(4))) float  f32x4;

// tanh(x) = 1 - 2/(exp(2x)+1); exact at +-inf, ~1e-6 rel err.
__device__ __forceinline__ float fast_tanh(float x) {
    float e = __expf(2.0f * x);
    return 1.0f - 2.0f * __builtin_amdgcn_rcpf(e + 1.0f);
}
__device__ __forceinline__ short f2bf(float f) {
    __hip_bfloat16 h = __float2bfloat16(f);      // RNE
    return *reinterpret_cast<short*>(&h);
}
__device__ __forceinline__ float bf2f(short s) {
    return __uint_as_float(((unsigned int)(unsigned short)s) << 16);
}

// ---- one-shot (per launch) fp32 -> bf16 weight repack into d_ws ----------
// W1b[idx][o][k32] (k 25..31 = 0), W2b[idx][o][k64] (k 50..63 = 0).
// d_ws is re-poisoned before every timed launch, so this runs every call.
__global__ void cvt_kernel(const float* __restrict__ W1,
                           const float* __restrict__ W2,
                           unsigned int* __restrict__ ws) {
    const int i = blockIdx.x * 256 + threadIdx.x;   // dword index
    if (i >= (W1B_SHORTS + W2B_SHORTS) / 2) return;
    float v0, v1;
    if (i < W1B_SHORTS / 2) {
        const int s = 2 * i;
        const int row = s >> 5, kk = s & 31;        // row = idx*50 + o
        const float* base = W1 + row * D0;
        v0 = (kk < D0) ? base[kk] : 0.f;
        v1 = (kk + 1 < D0) ? base[kk + 1] : 0.f;
    } else {
        const int s = 2 * i - W1B_SHORTS;
        const int row = s >> 6, kk = s & 63;        // row = idx*100 + o
        const float* base = W2 + row * D1;
        v0 = (kk < D1) ? base[kk] : 0.f;
        v1 = (kk + 1 < D1) ? base[kk + 1] : 0.f;
    }
    ws[i] = (unsigned int)(unsigned short)f2bf(v0)
          | ((unsigned int)(unsigned short)f2bf(v1) << 16);
}

__global__ __launch_bounds__(256, 1) void feat_kernel(
    const float* __restrict__ coords,
    const int*   __restrict__ types,
    const float* __restrict__ W0, const float* __restrict__ B0,
    const float* __restrict__ B1, const float* __restrict__ B2,
    const short* __restrict__ W1b, const short* __restrict__ W2b,
    float* __restrict__ out)
{
    // 27648 + 15360 + 3072 + 1344 + 32 = 47456 B -> 3 blocks/CU, 12 waves/CU
    __shared__ __attribute__((aligned(16))) short H1b[MROWS][H1STR];
    __shared__ __attribute__((aligned(16))) short H0b[MROWS][H0STR];
    __shared__ float4 E4[MROWS];        // env_a (w=0); zero on pad rows = mask
    __shared__ float  Ms[3][112];
    __shared__ int    cnt[2][4];        // per-wave type counts (waves 0,1 only)

    const int bn = blockIdx.x;    // b*128 + n
    const int b  = bn >> 7;
    const int n  = bn & 127;
    const int k  = threadIdx.x;   // 0..255
    const int wv = k >> 6;        // wave 0..3
    const int lq = (k >> 4) & 3;  // quad within wave
    const int ln = k & 15;
    const int lane = k & 63;

    // ---- zero LDS (pad rows/cols feed MFMA -> must be 0, never NaN)
    {
        const uint2 z2 = {0u, 0u};
        uint2* p1 = (uint2*)&H1b[0][0];
        for (int i = k; i < (MROWS * H1STR) / 4; i += 256) p1[i] = z2;
        uint2* p0 = (uint2*)&H0b[0][0];
        for (int i = k; i < (MROWS * H0STR) / 4; i += 256) p0[i] = z2;
        const float4 z4 = make_float4(0.f, 0.f, 0.f, 0.f);
        for (int i = k; i < MROWS; i += 256) E4[i] = z4;
    }

    // ---- ballot-based type counts + stable ranks (replaces O(N^2) sort)
    int tj = -1, j0 = 0;
    if (k < NB) { j0 = k + (k >= n ? 1 : 0); tj = types[j0]; }   // skip self
    const unsigned long long bm0 = __ballot(tj == 0);
    const unsigned long long bm1 = __ballot(tj == 1);
    const unsigned long long bm2 = __ballot(tj == 2);
    const unsigned long long bm3 = __ballot(tj == 3);
    if (lane == 0 && wv < 2) {
        cnt[wv][0] = __popcll(bm0); cnt[wv][1] = __popcll(bm1);
        cnt[wv][2] = __popcll(bm2); cnt[wv][3] = __popcll(bm3);
    }
    int sameBefore = 0;
    if (k < NB) {
        const unsigned long long mym =
            (tj == 0) ? bm0 : (tj == 1) ? bm1 : (tj == 2) ? bm2 : bm3;
        sameBefore = __popcll(mym & ((1ULL << lane) - 1ULL));
    }
    __syncthreads();

    const int c0 = cnt[0][0] + cnt[1][0];
    const int c1 = cnt[0][1] + cnt[1][1];
    const int c2 = cnt[0][2] + cnt[1][2];
    const int c3 = cnt[0][3] + cnt[1][3];
    const int ps1 = (c0 + 15) & ~15;
    const int ps2 = ps1 + ((c1 + 15) & ~15);
    const int ps3 = ps2 + ((c2 + 15) & ~15);
    const int tn  = types[n];

    // ======== phase 1: geometry + layer 0 (thread k -> its own padded row) ==
    if (k < NB) {
        const int idx = (tn << 2) | tj;
        const int pst = (tj == 0) ? 0 : (tj == 1) ? ps1 : (tj == 2) ? ps2 : ps3;
        const int pr  = pst + sameBefore + ((wv == 1) ? cnt[0][tj] : 0);

        const float cx = coords[(b * NATOM + n) * 3 + 0];
        const float cy = coords[(b * NATOM + n) * 3 + 1];
        const float cz = coords[(b * NATOM + n) * 3 + 2];
        const float dx = cx - coords[(b * NATOM + j0) * 3 + 0];
        const float dy = cy - coords[(b * NATOM + j0) * 3 + 1];
        const float dz = cz - coords[(b * NATOM + j0) * 3 + 2];
        const float d2   = dx * dx + dy * dy + dz * dz;
        const float inv  = rsqrtf(d2);         // 1/d (= env_r)
        const float inv2 = inv * inv;
        E4[pr] = make_float4(dx * inv2, dy * inv2, dz * inv2, 0.f);

        // layer 0: 1 -> 25 (idx divergent over <=4 types: 25 L1-hot loads)
        const float* w  = W0 + idx * D0;
        const float* bb = B0 + idx * D0;
        float h0[D0];
        #pragma unroll
        for (int o = 0; o < D0; ++o)
            h0[o] = fast_tanh(w[o] * inv + bb[o]);

        // store h0 bf16 (cols 25..31 stay 0 = K-pad for the 16x16x32 MFMA)
        unsigned int* dst = (unsigned int*)&H0b[pr][0];
        #pragma unroll
        for (int o = 0; o < D0 - 1; o += 2) {
            const unsigned int lo = (unsigned short)f2bf(h0[o]);
            const unsigned int hi = (unsigned short)f2bf(h0[o + 1]);
            dst[o >> 1] = lo | (hi << 16);
        }
        dst[12] = (unsigned int)(unsigned short)f2bf(h0[24]);   // hi half = 0
    }
    __syncthreads();

    // ======== phase 2a: layer 1 via MFMA (25 -> 50), K padded to 32 ========
    // A[m=ln][k=lq*8+j] from H0b (ds_read_b128); B[k][o1] = W1b row (short8).
    // C/D: col=ln (=o1), row=lq*4+r (=m). Pad-row garbage h1 is finite and
    // masked later by E=0 in the M-reduction.
    {
        const int o1   = wv * 16 + ln;         // 0..63
        const bool ov1 = (o1 < D1);
        const int o1c  = ov1 ? o1 : 0;         // clamp: pad lanes load row 0
        const int rres1 = (o1 < D0) ? o1 : o1 - D0;   // o1 % 25
        #pragma unroll
        for (int t = 0; t < 4; ++t) {
            const int cnt_t = (t == 0) ? c0 : (t == 1) ? c1 : (t == 2) ? c2 : c3;
            if (cnt_t == 0) continue;
            const int ps  = (t == 0) ? 0 : (t == 1) ? ps1 : (t == 2) ? ps2 : ps3;
            const int idx = (tn << 2) | t;
            const short8 bf =
                *(const short8*)(W1b + (idx * 50 + o1c) * 32 + lq * 8);
            const float b1v = ov1 ? B1[idx * D1 + o1] : 0.f;
            const int mtiles = (cnt_t + 15) >> 4;
            for (int mt = 0; mt < mtiles; ++mt) {
                const int mb = ps + mt * 16;
                const short8 af = *(const short8*)(&H0b[mb + ln][lq * 8]);
                f32x4 d = {0.f, 0.f, 0.f, 0.f};
                d = __builtin_amdgcn_mfma_f32_16x16x32_bf16(af, bf, d, 0, 0, 0);
                if (ov1) {                      // never touch cols >= 50 of H1b
                    #pragma unroll
                    for (int r = 0; r < 4; ++r) {
                        const int m = mb + lq * 4 + r;
                        const float h1v =
                            fast_tanh(d[r] + b1v) + bf2f(H0b[m][rres1]);
                        H1b[m][o1] = f2bf(h1v);
                    }
                }
            }
        }
    }
    __syncthreads();

    // ======== phase 2b: layer 2 via MFMA (50 -> 100) + fused M-reduce ======
    for (int nt = wv; nt < 7; nt += 4) {
        const int o  = nt * 16 + ln;           // output neuron
        const bool ov = (o < D2);
        const int oc = ov ? o : 0;             // clamped for safe addresses
        const int rres = oc % D1;              // residual column
        float Mc0 = 0.f, Mc1 = 0.f, Mc2 = 0.f;
        #pragma unroll
        for (int t = 0; t < 4; ++t) {
            const int cnt_t = (t == 0) ? c0 : (t == 1) ? c1 : (t == 2) ? c2 : c3;
            if (cnt_t == 0) continue;
            const int ps  = (t == 0) ? 0 : (t == 1) ? ps1 : (t == 2) ? ps2 : ps3;
            const int idx = (tn << 2) | t;
            const short* wr = W2b + (idx * 100 + oc) * 64;
            const short8 bf0 = *(const short8*)(wr + lq * 8);        // k<32
            const short8 bf1 = *(const short8*)(wr + 32 + lq * 8);   // K-pad=0
            const float b2n = B2[idx * D2 + oc];
            const int mtiles = (cnt_t + 15) >> 4;
            for (int mt = 0; mt < mtiles; ++mt) {
                const int mb = ps + mt * 16;
                const short* arow = &H1b[mb + ln][0];
                const short8 af0 = *(const short8*)(arow + lq * 8);
                const short8 af1 = *(const short8*)(arow + 32 + lq * 8);
                f32x4 d = {0.f, 0.f, 0.f, 0.f};
                d = __builtin_amdgcn_mfma_f32_16x16x32_bf16(af0, bf0, d, 0, 0, 0);
                d = __builtin_amdgcn_mfma_f32_16x16x32_bf16(af1, bf1, d, 0, 0, 0);
                #pragma unroll
                for (int r = 0; r < 4; ++r) {          // C/D: row = quad*4+r
                    const int m = mb + lq * 4 + r;
                    const float4 e = E4[m];            // 0 on pad rows = mask
                    const float g = fast_tanh(d[r] + b2n) + bf2f(H1b[m][rres]);
                    Mc0 += e.x * g; Mc1 += e.y * g; Mc2 += e.z * g;
                }
            }
        }
        // reduce across the 4 quads (rows); lanes differ only in lq
        Mc0 += __shfl_xor(Mc0, 16, 64); Mc1 += __shfl_xor(Mc1, 16, 64);
        Mc2 += __shfl_xor(Mc2, 16, 64);
        Mc0 += __shfl_xor(Mc0, 32, 64); Mc1 += __shfl_xor(Mc1, 32, 64);
        Mc2 += __shfl_xor(Mc2, 32, 64);
        if (lq == 0 && ov) {
            Ms[0][o] = Mc0; Ms[1][o] = Mc1; Ms[2][o] = Mc2;
        }
    }
    __syncthreads();

    // ======== phase 3: out[m][a] = sum_c M[c][m] * M[c][a], a < 4 ==========
    if (k < D2) {
        const float m0 = Ms[0][k], m1 = Ms[1][k], m2 = Ms[2][k];
        float4 o4;
        o4.x = m0 * Ms[0][0] + m1 * Ms[1][0] + m2 * Ms[2][0];
        o4.y = m0 * Ms[0][1] + m1 * Ms[1][1] + m2 * Ms[2][1];
        o4.z = m0 * Ms[0][2] + m1 * Ms[1][2] + m2 * Ms[2][2];
        o4.w = m0 * Ms[0][3] + m1 * Ms[1][3] + m2 * Ms[2][3];
        reinterpret_cast<float4*>(out)[bn * D2 + k] = o4;   // 16B-aligned
    }
}

extern "C" void kernel_launch(void* const* d_in, const int* in_sizes, int n_in,
                              void* d_out, int out_size, void* d_ws, size_t ws_size,
                              hipStream_t stream) {
    (void)in_sizes; (void)n_in; (void)out_size; (void)ws_size;
    const float* coords = (const float*)d_in[0];
    const int*   types  = (const int*)  d_in[1];
    const float* W0 = (const float*)d_in[2];
    const float* B0 = (const float*)d_in[3];
    const float* W1 = (const float*)d_in[4];
    const float* B1 = (const float*)d_in[5];
    const float* W2 = (const float*)d_in[6];
    const float* B2 = (const float*)d_in[7];
    float* out = (float*)d_out;

    short* W1b = (short*)d_ws;                 // 25600 shorts
    short* W2b = (short*)d_ws + W1B_SHORTS;    // 102400 shorts (offset 51200 B)

    // repack weights to bf16 (d_ws is re-poisoned before every timed launch)
    const int cvt_dwords = (W1B_SHORTS + W2B_SHORTS) / 2;      // 64000
    cvt_kernel<<<(cvt_dwords + 255) / 256, 256, 0, stream>>>(
        W1, W2, (unsigned int*)d_ws);

    feat_kernel<<<64 * NATOM, 256, 0, stream>>>(
        coords, types, W0, B0, B1, B2, W1b, W2b, out);
}